// Round 11
// baseline (1536.504 us; speedup 1.0000x reference)
//
#include <hip/hip_runtime.h>
#include <math.h>

#define EMBED   1024
#define HEADS   16
#define NEXP    8
#define HIDDEN  2752
#define HPAD    2816          // HIDDEN padded to 128 multiple (zero-filled)
#define SEQ     2048
#define BATCH   2
#define NTOK    (BATCH*SEQ)   // 4096

typedef _Float16 f16;
typedef __attribute__((ext_vector_type(8))) _Float16 f16x8;
typedef __attribute__((ext_vector_type(4))) float    f32x4;

// ---------------- workspace layout (float-unit offsets, all 16B aligned) ----------------
#define OFF_ROPE_C 0
#define OFF_ROPE_S (OFF_ROPE_C + 65536)
#define OFF_Q      (OFF_ROPE_S + 65536)           // q,k,v fp32; vth aliases Q after rope; act aliases later
#define OFF_K      (OFF_Q   + 4194304)
#define OFF_V      (OFF_K   + 4194304)
#define OFF_XN2    (OFF_V   + 4194304)            // qh/kh (f16) alias here until step 9 writes xn2
#define OFF_WSLOT  (OFF_XN2 + 4194304)
#define OFF_INTS   (OFF_WSLOT + 8192)             // counts[8] + lists[8*4096]
#define OFF_XN1H   (OFF_INTS + 40000)             // f16 4096x1024; aliased by attnh after QKV
#define OFF_XN2H   (OFF_XN1H + 2097152)
#define OFF_WQH    (OFF_XN2H + 2097152)
#define OFF_WKH    (OFF_WQH + 524288)
#define OFF_WVH    (OFF_WKH + 524288)
#define OFF_WOH    (OFF_WVH + 524288)
#define OFF_WGH    (OFF_WOH + 524288)             // [8][2816][1024] f16
#define OFF_WUH    (OFF_WGH + 11534336)
#define OFF_WDH    (OFF_WUH + 11534336)           // [8][1024][2816] f16

// bijective XCD-chunk swizzle: consecutive remapped ids stay on one XCD (nwg % 8 == 0)
__device__ __forceinline__ int xcd_swz(int flat, int nwg) {
    int per = nwg >> 3;
    return (flat & 7) * per + (flat >> 3);
}

// ---------------- RoPE tables (double precision) + zero counters ----------------
__global__ void rope_table_kernel(float* __restrict__ cosT, float* __restrict__ sinT,
                                  int* __restrict__ counts) {
    int idx = blockIdx.x * blockDim.x + threadIdx.x;
    if (blockIdx.x == 0 && threadIdx.x < NEXP) counts[threadIdx.x] = 0;
    if (idx >= SEQ * 32) return;
    int s = idx >> 5, d = idx & 31;
    double inv = pow(10000.0, -(double)(2 * d) / 64.0);
    double ang = (double)s * inv;
    cosT[idx] = (float)cos(ang);
    sinT[idx] = (float)sin(ang);
}

// ---------------- transpose + fp32->fp16: src[K][N] -> dst[NP][KP], zero-padded ----------------
__global__ __launch_bounds__(256) void transpose_f32_f16(const float* __restrict__ src,
                                                         f16* __restrict__ dst,
                                                         int K, int N, int KP, int NP,
                                                         long sstride, long dstride) {
    src += (size_t)blockIdx.z * sstride;
    dst += (size_t)blockIdx.z * dstride;
    __shared__ float t[64][65];
    int kb = blockIdx.x * 64, nb = blockIdx.y * 64;
    int tid = threadIdx.x;
    int nc = (tid & 15) * 4, kr = tid >> 4;
#pragma unroll
    for (int r = 0; r < 4; r++) {
        int k = kb + kr + r * 16;
        float4 v = {0.f, 0.f, 0.f, 0.f};
        if (k < K && nb + nc < N)
            v = *(const float4*)&src[(size_t)k * N + nb + nc];
        t[nc + 0][kr + r * 16] = v.x;
        t[nc + 1][kr + r * 16] = v.y;
        t[nc + 2][kr + r * 16] = v.z;
        t[nc + 3][kr + r * 16] = v.w;
    }
    __syncthreads();
    int kc = (tid & 7) * 8, nr = tid >> 3;
#pragma unroll
    for (int r = 0; r < 2; r++) {
        int n = nr + r * 32;
        f16x8 o;
#pragma unroll
        for (int i = 0; i < 8; i++) o[i] = (f16)t[n][kc + i];
        *(f16x8*)&dst[(size_t)(nb + n) * KP + kb + kc] = o;
    }
}

// ---------------- RMSNorm: one block per token; writes f16 (and optional f32) ----------------
template<int DUAL>
__global__ __launch_bounds__(256) void rmsnorm_kernel(const float* __restrict__ x,
                                                      const float* __restrict__ g,
                                                      float* __restrict__ o32,
                                                      f16* __restrict__ o16) {
    int t = blockIdx.x;
    int tid = threadIdx.x;
    const float4* xr = (const float4*)(x + (size_t)t * EMBED);
    float4 v = xr[tid];
    float ss = v.x*v.x + v.y*v.y + v.z*v.z + v.w*v.w;
#pragma unroll
    for (int off = 1; off < 64; off <<= 1) ss += __shfl_xor(ss, off);
    __shared__ float red[4];
    if ((tid & 63) == 0) red[tid >> 6] = ss;
    __syncthreads();
    float tot = red[0] + red[1] + red[2] + red[3];
    float rr = 1.0f / sqrtf(tot * (1.0f / EMBED) + 1e-6f);
    float4 gv = ((const float4*)g)[tid];
    float4 ov;
    ov.x = v.x * rr * gv.x; ov.y = v.y * rr * gv.y;
    ov.z = v.z * rr * gv.z; ov.w = v.w * rr * gv.w;
    if (DUAL) ((float4*)(o32 + (size_t)t * EMBED))[tid] = ov;
    typedef __attribute__((ext_vector_type(4))) _Float16 f16x4;
    f16x4 oh; oh[0] = (f16)ov.x; oh[1] = (f16)ov.y; oh[2] = (f16)ov.z; oh[3] = (f16)ov.w;
    *(f16x4*)(o16 + (size_t)t * EMBED + tid * 4) = oh;
}

// ---------------- fused QKV: barrier-free, register double-buffered MFMA GEMM ----------------
// 1D grid 768 = 32(x) * 8(y) * 3(sel); XCD-swizzled
__global__ __launch_bounds__(256) void gemm_qkv(const f16* __restrict__ xh,
                                                const f16* __restrict__ wqh,
                                                const f16* __restrict__ wkh,
                                                const f16* __restrict__ wvh,
                                                float* __restrict__ q,
                                                float* __restrict__ k,
                                                float* __restrict__ v) {
    int wgid = xcd_swz(blockIdx.x, 768);
    int sel = wgid >> 8;
    int rem = wgid & 255;
    int bm = (rem & 31) * 128, bn = (rem >> 5) * 128;
    const f16* B = (sel == 0) ? wqh : (sel == 1) ? wkh : wvh;
    float* C = (sel == 0) ? q : (sel == 1) ? k : v;
    int tid = threadIdx.x, lane = tid & 63, w = tid >> 6;
    int wr = w >> 1, wc = w & 1;
    const f16* ar[4]; const f16* br[4];
#pragma unroll
    for (int m = 0; m < 4; m++)
        ar[m] = xh + (size_t)(bm + (wr * 4 + m) * 16 + (lane & 15)) * 1024 + (lane >> 4) * 8;
#pragma unroll
    for (int n = 0; n < 4; n++)
        br[n] = B + (size_t)(bn + (wc * 4 + n) * 16 + (lane & 15)) * 1024 + (lane >> 4) * 8;
    f32x4 acc[4][4] = {};
    f16x8 aA[4], bA[4], aB[4], bB[4];
    auto LD = [&](f16x8* A, f16x8* Bv, int k0) {
#pragma unroll
        for (int m = 0; m < 4; m++) A[m] = *(const f16x8*)(ar[m] + k0);
#pragma unroll
        for (int n = 0; n < 4; n++) Bv[n] = *(const f16x8*)(br[n] + k0);
    };
    auto FMA = [&](f16x8* A, f16x8* Bv) {
#pragma unroll
        for (int n = 0; n < 4; n++)
#pragma unroll
            for (int m = 0; m < 4; m++)
                acc[m][n] = __builtin_amdgcn_mfma_f32_16x16x32_f16(A[m], Bv[n], acc[m][n], 0, 0, 0);
    };
    LD(aA, bA, 0);
#pragma unroll 1
    for (int k0 = 0; k0 < 1024 - 64; k0 += 64) {
        LD(aB, bB, k0 + 32);     // prefetch next while computing current
        FMA(aA, bA);
        LD(aA, bA, k0 + 64);
        FMA(aB, bB);
    }
    LD(aB, bB, 1024 - 32);
    FMA(aA, bA);
    FMA(aB, bB);
#pragma unroll
    for (int m = 0; m < 4; m++)
#pragma unroll
        for (int r = 0; r < 4; r++) {
            int row = bm + (wr * 4 + m) * 16 + (lane >> 4) * 4 + r;
            float* crow = C + (size_t)row * 1024 + bn + (lane & 15);
#pragma unroll
            for (int n = 0; n < 4; n++) crow[(wc * 4 + n) * 16] = acc[m][n][r];
        }
}

// ---------------- WO GEMM + residual, register double-buffered ----------------
__global__ __launch_bounds__(256) void gemm_wo(const f16* __restrict__ ah,
                                               const f16* __restrict__ wh,
                                               const float* __restrict__ R,
                                               float* __restrict__ C) {
    int wgid = xcd_swz(blockIdx.x, 256);
    int bm = (wgid & 31) * 128, bn = (wgid >> 5) * 128;
    int tid = threadIdx.x, lane = tid & 63, w = tid >> 6;
    int wr = w >> 1, wc = w & 1;
    const f16* ar[4]; const f16* br[4];
#pragma unroll
    for (int m = 0; m < 4; m++)
        ar[m] = ah + (size_t)(bm + (wr * 4 + m) * 16 + (lane & 15)) * 1024 + (lane >> 4) * 8;
#pragma unroll
    for (int n = 0; n < 4; n++)
        br[n] = wh + (size_t)(bn + (wc * 4 + n) * 16 + (lane & 15)) * 1024 + (lane >> 4) * 8;
    f32x4 acc[4][4] = {};
    f16x8 aA[4], bA[4], aB[4], bB[4];
    auto LD = [&](f16x8* A, f16x8* Bv, int k0) {
#pragma unroll
        for (int m = 0; m < 4; m++) A[m] = *(const f16x8*)(ar[m] + k0);
#pragma unroll
        for (int n = 0; n < 4; n++) Bv[n] = *(const f16x8*)(br[n] + k0);
    };
    auto FMA = [&](f16x8* A, f16x8* Bv) {
#pragma unroll
        for (int n = 0; n < 4; n++)
#pragma unroll
            for (int m = 0; m < 4; m++)
                acc[m][n] = __builtin_amdgcn_mfma_f32_16x16x32_f16(A[m], Bv[n], acc[m][n], 0, 0, 0);
    };
    LD(aA, bA, 0);
#pragma unroll 1
    for (int k0 = 0; k0 < 1024 - 64; k0 += 64) {
        LD(aB, bB, k0 + 32);
        FMA(aA, bA);
        LD(aA, bA, k0 + 64);
        FMA(aB, bB);
    }
    LD(aB, bB, 1024 - 32);
    FMA(aA, bA);
    FMA(aB, bB);
#pragma unroll
    for (int m = 0; m < 4; m++)
#pragma unroll
        for (int r = 0; r < 4; r++) {
            int row = bm + (wr * 4 + m) * 16 + (lane >> 4) * 4 + r;
            const float* rrow = R + (size_t)row * 1024 + bn + (lane & 15);
            float* crow = C + (size_t)row * 1024 + bn + (lane & 15);
#pragma unroll
            for (int n = 0; n < 4; n++) crow[(wc * 4 + n) * 16] = acc[m][n][r] + rrow[(wc * 4 + n) * 16];
        }
}

// ---------------- RoPE apply: fp32 q,k -> f16 qh,kh ----------------
__global__ void rope_kernel(const float* __restrict__ q, const float* __restrict__ k,
                            f16* __restrict__ qh, f16* __restrict__ kh,
                            const float* __restrict__ cosT, const float* __restrict__ sinT) {
    int idx = blockIdx.x * blockDim.x + threadIdx.x;
    if (idx >= NTOK * HEADS * 32) return;
    int d = idx & 31;
    int h = (idx >> 5) & 15;
    int t = idx >> 9;
    int s = t & (SEQ - 1);
    float c = cosT[s * 32 + d], sn = sinT[s * 32 + d];
    size_t base = (size_t)t * EMBED + h * 64;
    float q1 = q[base + d], q2 = q[base + d + 32];
    qh[base + d]      = (f16)(q1 * c - q2 * sn);
    qh[base + d + 32] = (f16)(q2 * c + q1 * sn);
    float k1 = k[base + d], k2 = k[base + d + 32];
    kh[base + d]      = (f16)(k1 * c - k2 * sn);
    kh[base + d + 32] = (f16)(k2 * c + k1 * sn);
}

// ---------------- V transpose: fp32 v[tok][1024] -> f16 vth[b][h][64 d][2048 s] ----------------
__global__ __launch_bounds__(256) void vt_kernel(const float* __restrict__ v,
                                                 f16* __restrict__ vth) {
    int bh = blockIdx.y, b = bh >> 4, h = bh & 15;
    int s0 = blockIdx.x * 64;
    __shared__ float t[64][65];   // t[d][s]
    int tid = threadIdx.x;
    int sl = tid >> 4, dc = (tid & 15) * 4;
#pragma unroll
    for (int r = 0; r < 4; r++) {
        int s = sl + r * 16;
        float4 vv = *(const float4*)&v[(size_t)(b * SEQ + s0 + s) * 1024 + h * 64 + dc];
        t[dc + 0][s] = vv.x; t[dc + 1][s] = vv.y;
        t[dc + 2][s] = vv.z; t[dc + 3][s] = vv.w;
    }
    __syncthreads();
    int dl = tid >> 3, sc = (tid & 7) * 8;
#pragma unroll
    for (int r = 0; r < 2; r++) {
        int d = dl + r * 32;
        f16x8 o;
#pragma unroll
        for (int i = 0; i < 8; i++) o[i] = (f16)t[d][sc + i];
        *(f16x8*)&vth[((size_t)(b * 16 + h) * 64 + d) * 2048 + s0 + sc] = o;
    }
}

// ---------------- MFMA flash attention: barrier-free, 4 waves x 16 q-rows ----------------
// grid 1024 = 32 bh * 32 qt; XCD-swizzled so same (b,h) K/V stays L2-resident
__global__ __launch_bounds__(256) void attn_mfma(const f16* __restrict__ qh,
                                                 const f16* __restrict__ kh,
                                                 const f16* __restrict__ vth,
                                                 f16* __restrict__ oh) {
    int wgid = xcd_swz(blockIdx.x, 1024);
    int bh = wgid >> 5, qt = wgid & 31;
    int b = bh >> 4, h = bh & 15;
    int tid = threadIdx.x, lane = tid & 63, w = tid >> 6;
    __shared__ __align__(16) f16 plds[4][16][40];   // per-wave P tile, padded rows (80B)
    int lr = lane & 15, lc = lane >> 4;
    int wq0 = qt * 64 + w * 16;                     // sequence-local first q row of this wave
    const f16* qbase = qh + (size_t)(b * SEQ + wq0 + lr) * 1024 + h * 64 + lc * 8;
    f16x8 qa0 = *(const f16x8*)qbase;
    f16x8 qa1 = *(const f16x8*)(qbase + 32);
    f32x4 O[4] = {};                                 // O[dn]: col=dn*16+lr, row=lc*4+r
    float mrow[4], lrow[4];
#pragma unroll
    for (int r = 0; r < 4; r++) { mrow[r] = -INFINITY; lrow[r] = 0.f; }
    const f16* kbase = kh + (size_t)(b * SEQ + lr) * 1024 + h * 64 + lc * 8;
    const f16* vbase = vth + ((size_t)(b * 16 + h) * 64 + lr) * 2048 + lc * 8;
    int qmax = wq0 + 15;
#pragma unroll 1
    for (int kv0 = 0; kv0 <= qmax; kv0 += 32) {
        f32x4 s0v = {}, s1v = {};
        {
            const f16* kp0 = kbase + (size_t)kv0 * 1024;
            const f16* kp1 = kbase + (size_t)(kv0 + 16) * 1024;
            f16x8 ka0 = *(const f16x8*)kp0;
            f16x8 ka1 = *(const f16x8*)(kp0 + 32);
            f16x8 kb0 = *(const f16x8*)kp1;
            f16x8 kb1 = *(const f16x8*)(kp1 + 32);
            s0v = __builtin_amdgcn_mfma_f32_16x16x32_f16(qa0, ka0, s0v, 0, 0, 0);
            s0v = __builtin_amdgcn_mfma_f32_16x16x32_f16(qa1, ka1, s0v, 0, 0, 0);
            s1v = __builtin_amdgcn_mfma_f32_16x16x32_f16(qa0, kb0, s1v, 0, 0, 0);
            s1v = __builtin_amdgcn_mfma_f32_16x16x32_f16(qa1, kb1, s1v, 0, 0, 0);
        }
        bool tail = (kv0 + 31 > wq0);
#pragma unroll
        for (int r = 0; r < 4; r++) {
            float a = s0v[r] * 0.125f;
            float c = s1v[r] * 0.125f;
            if (tail) {
                int qg = wq0 + lc * 4 + r;
                if (kv0 + lr > qg)      a = -INFINITY;
                if (kv0 + 16 + lr > qg) c = -INFINITY;
            }
            s0v[r] = a; s1v[r] = c;
        }
        float mt[4], lt[4], sco[4];
#pragma unroll
        for (int r = 0; r < 4; r++) mt[r] = fmaxf(s0v[r], s1v[r]);
#pragma unroll
        for (int off = 1; off < 16; off <<= 1)
#pragma unroll
            for (int r = 0; r < 4; r++) mt[r] = fmaxf(mt[r], __shfl_xor(mt[r], off));
#pragma unroll
        for (int r = 0; r < 4; r++) {
            float mn = fmaxf(mrow[r], mt[r]);
            sco[r] = expf(mrow[r] - mn);
            mrow[r] = mn;
            s0v[r] = expf(s0v[r] - mn);
            s1v[r] = expf(s1v[r] - mn);
            lt[r] = s0v[r] + s1v[r];
        }
#pragma unroll
        for (int off = 1; off < 16; off <<= 1)
#pragma unroll
            for (int r = 0; r < 4; r++) lt[r] += __shfl_xor(lt[r], off);
#pragma unroll
        for (int r = 0; r < 4; r++) lrow[r] = lrow[r] * sco[r] + lt[r];
#pragma unroll
        for (int dn = 0; dn < 4; dn++)
#pragma unroll
            for (int r = 0; r < 4; r++) O[dn][r] *= sco[r];
#pragma unroll
        for (int r = 0; r < 4; r++) {
            plds[w][lc * 4 + r][lr]      = (f16)s0v[r];
            plds[w][lc * 4 + r][16 + lr] = (f16)s1v[r];
        }
        f16x8 pa = *(const f16x8*)&plds[w][lr][lc * 8];
#pragma unroll
        for (int dn = 0; dn < 4; dn++) {
            f16x8 vb = *(const f16x8*)(vbase + (size_t)(dn * 16) * 2048 + kv0);
            O[dn] = __builtin_amdgcn_mfma_f32_16x16x32_f16(pa, vb, O[dn], 0, 0, 0);
        }
    }
#pragma unroll
    for (int r = 0; r < 4; r++) {
        float inv = 1.0f / lrow[r];
        size_t row = (size_t)(b * SEQ + wq0 + lc * 4 + r) * 1024 + h * 64 + lr;
#pragma unroll
        for (int dn = 0; dn < 4; dn++)
            oh[row + dn * 16] = (f16)(O[dn][r] * inv);
    }
}

// ---------------- router: one wave per token, top-2 dispatch (fp32) ----------------
__global__ __launch_bounds__(64) void router_kernel(const float* __restrict__ xn2,
                                                    const float* __restrict__ wr,
                                                    float* __restrict__ wslot,
                                                    int* __restrict__ counts,
                                                    int* __restrict__ lists) {
    int t = blockIdx.x;
    int lane = threadIdx.x;
    float acc[NEXP] = {};
    for (int i = lane; i < EMBED; i += 64) {
        float xv = xn2[(size_t)t * EMBED + i];
        const float* wrow = wr + (size_t)i * NEXP;
#pragma unroll
        for (int e = 0; e < NEXP; e++) acc[e] = fmaf(xv, wrow[e], acc[e]);
    }
#pragma unroll
    for (int off = 1; off < 64; off <<= 1)
#pragma unroll
        for (int e = 0; e < NEXP; e++) acc[e] += __shfl_xor(acc[e], off);
    if (lane == 0) {
        int e1 = 0; float b1 = acc[0];
#pragma unroll
        for (int e = 1; e < NEXP; e++) if (acc[e] > b1) { b1 = acc[e]; e1 = e; }
        int e2 = -1; float b2 = -INFINITY;
#pragma unroll
        for (int e = 0; e < NEXP; e++) if (e != e1 && acc[e] > b2) { b2 = acc[e]; e2 = e; }
        float p2 = expf(b2 - b1);
        float inv = 1.0f / (1.0f + p2);
        int pos1 = atomicAdd(&counts[e1], 1);
        lists[e1 * NTOK + pos1] = (t << 1) | 0;
        wslot[t * 2 + 0] = inv;
        int pos2 = atomicAdd(&counts[e2], 1);
        lists[e2 * NTOK + pos2] = (t << 1) | 1;
        wslot[t * 2 + 1] = p2 * inv;
    }
}

// ---------------- MoE gate+up, register double-buffered: block 128x64 ----------------
__global__ __launch_bounds__(256) void moe_gateup_mfma(const f16* __restrict__ xh2,
                                                       const f16* __restrict__ wgh,
                                                       const f16* __restrict__ wuh,
                                                       const int* __restrict__ lists,
                                                       const int* __restrict__ counts,
                                                       f16* __restrict__ act) {
    int wgid = xcd_swz(blockIdx.x, 32 * 44 * NEXP);
    int e = wgid / (32 * 44);
    int rem = wgid % (32 * 44);
    int bx = rem & 31, by = rem >> 5;
    int cnt = counts[e];
    int bm = bx * 128;
    if (bm >= cnt) return;
    int bn = by * 64;
    __shared__ int toks[128];
    int tid = threadIdx.x, lane = tid & 63, w = tid >> 6;
    int wr = w >> 1, wc = w & 1;
    if (tid < 128) {
        int i = bm + tid;
        toks[tid] = lists[e * NTOK + ((i < cnt) ? i : (cnt - 1))];
    }
    __syncthreads();
    const f16* wgb = wgh + (size_t)e * HPAD * 1024;
    const f16* wub = wuh + (size_t)e * HPAD * 1024;
    const f16* ar[4]; const f16* gr[2]; const f16* ur[2];
#pragma unroll
    for (int m = 0; m < 4; m++) {
        int entry = toks[(wr * 4 + m) * 16 + (lane & 15)];
        ar[m] = xh2 + (size_t)(entry >> 1) * 1024 + (lane >> 4) * 8;
    }
#pragma unroll
    for (int n = 0; n < 2; n++) {
        int col = bn + (wc * 2 + n) * 16 + (lane & 15);
        gr[n] = wgb + (size_t)col * 1024 + (lane >> 4) * 8;
        ur[n] = wub + (size_t)col * 1024 + (lane >> 4) * 8;
    }
    f32x4 aG[4][2] = {}, aU[4][2] = {};
    f16x8 aA[4], gA[2], uA[2], aB[4], gB[2], uB[2];
    auto LD = [&](f16x8* A, f16x8* G, f16x8* U, int k0) {
#pragma unroll
        for (int m = 0; m < 4; m++) A[m] = *(const f16x8*)(ar[m] + k0);
#pragma unroll
        for (int n = 0; n < 2; n++) { G[n] = *(const f16x8*)(gr[n] + k0); U[n] = *(const f16x8*)(ur[n] + k0); }
    };
    auto FMA = [&](f16x8* A, f16x8* G, f16x8* U) {
#pragma unroll
        for (int n = 0; n < 2; n++)
#pragma unroll
            for (int m = 0; m < 4; m++) {
                aG[m][n] = __builtin_amdgcn_mfma_f32_16x16x32_f16(A[m], G[n], aG[m][n], 0, 0, 0);
                aU[m][n] = __builtin_amdgcn_mfma_f32_16x16x32_f16(A[m], U[n], aU[m][n], 0, 0, 0);
            }
    };
    LD(aA, gA, uA, 0);
#pragma unroll 1
    for (int k0 = 0; k0 < 1024 - 64; k0 += 64) {
        LD(aB, gB, uB, k0 + 32);
        FMA(aA, gA, uA);
        LD(aA, gA, uA, k0 + 64);
        FMA(aB, gB, uB);
    }
    LD(aB, gB, uB, 1024 - 32);
    FMA(aA, gA, uA);
    FMA(aB, gB, uB);
#pragma unroll
    for (int m = 0; m < 4; m++)
#pragma unroll
        for (int r = 0; r < 4; r++) {
            int rl = (wr * 4 + m) * 16 + (lane >> 4) * 4 + r;
            if (bm + rl < cnt) {
                int entry = toks[rl];
                f16* arow = act + (size_t)entry * HPAD + bn + (lane & 15);
#pragma unroll
                for (int n = 0; n < 2; n++) {
                    float g = aG[m][n][r], u = aU[m][n][r];
                    arow[(wc * 2 + n) * 16] = (f16)(g / (1.0f + expf(-g)) * u);
                }
            }
        }
}

// ---------------- MoE down, register double-buffered: block 128x128 ----------------
__global__ __launch_bounds__(256) void moe_down_mfma(const f16* __restrict__ act,
                                                     const f16* __restrict__ wdh,
                                                     const int* __restrict__ lists,
                                                     const int* __restrict__ counts,
                                                     const float* __restrict__ wslot,
                                                     float* __restrict__ out) {
    int wgid = xcd_swz(blockIdx.x, 32 * 8 * NEXP);
    int e = wgid >> 8;
    int rem = wgid & 255;
    int bx = rem & 31, by = rem >> 5;
    int cnt = counts[e];
    int bm = bx * 128;
    if (bm >= cnt) return;
    int bn = by * 128;
    __shared__ int toks[128];
    int tid = threadIdx.x, lane = tid & 63, w = tid >> 6;
    int wr = w >> 1, wc = w & 1;
    if (tid < 128) {
        int i = bm + tid;
        toks[tid] = lists[e * NTOK + ((i < cnt) ? i : (cnt - 1))];
    }
    __syncthreads();
    const f16* wdb = wdh + (size_t)e * 1024 * HPAD;
    const f16* ar[4]; const f16* br[4];
#pragma unroll
    for (int m = 0; m < 4; m++) {
        int entry = toks[(wr * 4 + m) * 16 + (lane & 15)];
        ar[m] = act + (size_t)entry * HPAD + (lane >> 4) * 8;
    }
#pragma unroll
    for (int n = 0; n < 4; n++)
        br[n] = wdb + (size_t)(bn + (wc * 4 + n) * 16 + (lane & 15)) * HPAD + (lane >> 4) * 8;
    f32x4 acc[4][4] = {};
    f16x8 aA[4], bA[4], aB[4], bB[4];
    auto LD = [&](f16x8* A, f16x8* Bv, int k0) {
#pragma unroll
        for (int m = 0; m < 4; m++) A[m] = *(const f16x8*)(ar[m] + k0);
#pragma unroll
        for (int n = 0; n < 4; n++) Bv[n] = *(const f16x8*)(br[n] + k0);
    };
    auto FMA = [&](f16x8* A, f16x8* Bv) {
#pragma unroll
        for (int n = 0; n < 4; n++)
#pragma unroll
            for (int m = 0; m < 4; m++)
                acc[m][n] = __builtin_amdgcn_mfma_f32_16x16x32_f16(A[m], Bv[n], acc[m][n], 0, 0, 0);
    };
    LD(aA, bA, 0);
#pragma unroll 1
    for (int k0 = 0; k0 < HPAD - 64; k0 += 64) {
        LD(aB, bB, k0 + 32);
        FMA(aA, bA);
        LD(aA, bA, k0 + 64);
        FMA(aB, bB);
    }
    LD(aB, bB, HPAD - 32);
    FMA(aA, bA);
    FMA(aB, bB);
#pragma unroll
    for (int m = 0; m < 4; m++)
#pragma unroll
        for (int r = 0; r < 4; r++) {
            int rl = (wr * 4 + m) * 16 + (lane >> 4) * 4 + r;
            if (bm + rl < cnt) {
                int entry = toks[rl];
                float wgt = wslot[entry];
                float* orow = out + (size_t)(entry >> 1) * 1024 + bn + (lane & 15);
#pragma unroll
                for (int n = 0; n < 4; n++)
                    atomicAdd(orow + (wc * 4 + n) * 16, wgt * acc[m][n][r]);
            }
        }
}

// ---------------- launch ----------------
extern "C" void kernel_launch(void* const* d_in, const int* in_sizes, int n_in,
                              void* d_out, int out_size, void* d_ws, size_t ws_size,
                              hipStream_t stream) {
    (void)in_sizes; (void)n_in; (void)out_size; (void)ws_size;
    const float* x  = (const float*)d_in[0];
    const float* wq = (const float*)d_in[1];
    const float* wk = (const float*)d_in[2];
    const float* wv = (const float*)d_in[3];
    const float* wo = (const float*)d_in[4];
    const float* wr = (const float*)d_in[5];
    const float* wg = (const float*)d_in[6];
    const float* wu = (const float*)d_in[7];
    const float* wd = (const float*)d_in[8];
    const float* g1 = (const float*)d_in[9];
    const float* g2 = (const float*)d_in[10];
    float* out = (float*)d_out;

    float* ws    = (float*)d_ws;
    float* ropeC = ws + OFF_ROPE_C;
    float* ropeS = ws + OFF_ROPE_S;
    float* qb    = ws + OFF_Q;
    float* kb    = ws + OFF_K;
    float* vb    = ws + OFF_V;
    float* xn2   = ws + OFF_XN2;
    float* wslot = ws + OFF_WSLOT;
    int*   counts = (int*)(ws + OFF_INTS);
    int*   lists  = counts + NEXP;
    f16* xn1h  = (f16*)(ws + OFF_XN1H);
    f16* attnh = xn1h;                       // alias: xn1h dead after QKV
    f16* xn2h  = (f16*)(ws + OFF_XN2H);
    f16* wqh   = (f16*)(ws + OFF_WQH);
    f16* wkh   = (f16*)(ws + OFF_WKH);
    f16* wvh   = (f16*)(ws + OFF_WVH);
    f16* woh   = (f16*)(ws + OFF_WOH);
    f16* wgh   = (f16*)(ws + OFF_WGH);
    f16* wuh   = (f16*)(ws + OFF_WUH);
    f16* wdh   = (f16*)(ws + OFF_WDH);
    f16* act   = (f16*)(ws + OFF_Q);         // alias: q,k,v dead after attention
    f16* qh    = (f16*)(ws + OFF_XN2);       // alias: xn2 fp32 written only at step 9
    f16* kh    = qh + (size_t)NTOK * EMBED;
    f16* vth   = (f16*)(ws + OFF_Q);         // alias: q fp32 dead after rope

    // 1. rope tables (+ zero expert counters)
    rope_table_kernel<<<(SEQ * 32 + 255) / 256, 256, 0, stream>>>(ropeC, ropeS, counts);
    // 2. weight transposes fp32 -> fp16 [N][K]
    transpose_f32_f16<<<dim3(16, 16, 1), 256, 0, stream>>>(wq, wqh, 1024, 1024, 1024, 1024, 0, 0);
    transpose_f32_f16<<<dim3(16, 16, 1), 256, 0, stream>>>(wk, wkh, 1024, 1024, 1024, 1024, 0, 0);
    transpose_f32_f16<<<dim3(16, 16, 1), 256, 0, stream>>>(wv, wvh, 1024, 1024, 1024, 1024, 0, 0);
    transpose_f32_f16<<<dim3(16, 16, 1), 256, 0, stream>>>(wo, woh, 1024, 1024, 1024, 1024, 0, 0);
    transpose_f32_f16<<<dim3(16, 44, 8), 256, 0, stream>>>(wg, wgh, 1024, HIDDEN, 1024, HPAD,
                                                           (long)1024 * HIDDEN, (long)HPAD * 1024);
    transpose_f32_f16<<<dim3(16, 44, 8), 256, 0, stream>>>(wu, wuh, 1024, HIDDEN, 1024, HPAD,
                                                           (long)1024 * HIDDEN, (long)HPAD * 1024);
    transpose_f32_f16<<<dim3(44, 16, 8), 256, 0, stream>>>(wd, wdh, HIDDEN, 1024, HPAD, 1024,
                                                           (long)HIDDEN * 1024, (long)1024 * HPAD);
    // 3. rmsnorm(x,g1) -> xn1h (f16)
    rmsnorm_kernel<0><<<NTOK, 256, 0, stream>>>(x, g1, nullptr, xn1h);
    // 4. QKV projections (MFMA, reg-dbuf) -> fp32 q,k,v
    gemm_qkv<<<768, 256, 0, stream>>>(xn1h, wqh, wkh, wvh, qb, kb, vb);
    // 5. rope: fp32 q,k -> f16 qh,kh
    rope_kernel<<<(NTOK * HEADS * 32 + 255) / 256, 256, 0, stream>>>(qb, kb, qh, kh, ropeC, ropeS);
    // 6. V transpose: fp32 v -> f16 vth (overwrites dead q fp32)
    vt_kernel<<<dim3(32, 32), 256, 0, stream>>>(vb, vth);
    // 7. MFMA flash attention -> attnh (f16)
    attn_mfma<<<1024, 256, 0, stream>>>(qh, kh, vth, attnh);
    // 8. out-proj + residual -> out (= h)
    gemm_wo<<<256, 256, 0, stream>>>(attnh, woh, x, out);
    // 9. rmsnorm(h,g2) -> xn2 (fp32, overwrites dead qh/kh) + xn2h (f16)
    rmsnorm_kernel<1><<<NTOK, 256, 0, stream>>>(out, g2, xn2, xn2h);
    // 10. router + top-2 dispatch
    router_kernel<<<NTOK, 64, 0, stream>>>(xn2, wr, wslot, counts, lists);
    // 11. fused gate+up (reg-dbuf) -> act (f16, aliases q/k/v)
    moe_gateup_mfma<<<32 * 44 * NEXP, 256, 0, stream>>>(xn2h, wgh, wuh, lists, counts, act);
    // 12. down (reg-dbuf) + weighted scatter-add into out
    moe_down_mfma<<<32 * 8 * NEXP, 256, 0, stream>>>(act, wdh, lists, counts, wslot, out);
}